// Round 11
// baseline (534.553 us; speedup 1.0000x reference)
//
#include <hip/hip_runtime.h>
#include <hip/hip_bf16.h>
#include <cstdint>

typedef __bf16 bf16;
typedef bf16 bf16x4 __attribute__((ext_vector_type(4)));
typedef bf16 bf16x8 __attribute__((ext_vector_type(8)));
typedef float f32x4 __attribute__((ext_vector_type(4)));
typedef float f32x16 __attribute__((ext_vector_type(16)));
typedef uint32_t u32x4 __attribute__((ext_vector_type(4)));

#define NB 16
#define NL 1025
#define NDIM 1024
#define NHEADS 16
#define NCOND 256
#define NBH (NB*NHEADS)       // 256
#define NML (NB*NL)           // 16400
#define LP 1056               // padded kv length for v^T rows
#define QTILES 17             // ceil(1025/64)  (rope tiling)
#define NSLOT 17              // attn: balanced 32-row q-tile slots per bh
#define QSCALE (0.125f * 1.44269504088896340736f)  // sm_scale * log2(e)

__device__ __forceinline__ void gload16(const void* g, void* l) {
  __builtin_amdgcn_global_load_lds(
      (const __attribute__((address_space(1))) void*)(uintptr_t)g,
      (__attribute__((address_space(3))) void*)(uintptr_t)l,
      16, 0, 0);
}

__device__ __forceinline__ float fexp2(float x) {
  return __builtin_amdgcn_exp2f(x);   // raw v_exp_f32; exp2(-1e30) -> 0
}

__device__ __forceinline__ uint32_t cvtpk(float lo, float hi) {
  uint32_t r;
  asm("v_cvt_pk_bf16_f32 %0, %1, %2" : "=v"(r) : "v"(lo), "v"(hi));
  return r;   // lo -> bits [15:0], hi -> bits [31:16]
}

__device__ __forceinline__ f32x16 zero16() {
  f32x16 z;
#pragma unroll
  for (int i = 0; i < 16; ++i) z[i] = 0.f;
  return z;
}

// ---------------- scale = cond @ w_norm^T + 1 ----------------
__global__ __launch_bounds__(256) void k_scale(const float* __restrict__ cond,
                                               const float* __restrict__ wn,
                                               float* __restrict__ scl) {
  __shared__ float cs[NCOND];
  const int b = blockIdx.x, t = threadIdx.x;
  cs[t] = cond[b * NCOND + t];
  __syncthreads();
#pragma unroll
  for (int dd = 0; dd < 4; ++dd) {
    const int d = t * 4 + dd;
    const float4* w = (const float4*)(wn + (size_t)d * NCOND);
    float acc = 1.0f;
    for (int c4 = 0; c4 < NCOND / 4; ++c4) {
      float4 wv = w[c4];
      acc += wv.x * cs[c4*4] + wv.y * cs[c4*4+1] + wv.z * cs[c4*4+2] + wv.w * cs[c4*4+3];
    }
    scl[b * NDIM + d] = acc;
  }
}

// ---------------- fp32 -> bf16 cast ----------------
__global__ __launch_bounds__(256) void k_cast(const float* __restrict__ src,
                                              bf16* __restrict__ dst, int n) {
  const int i = (blockIdx.x * 256 + threadIdx.x) * 4;
  if (i < n) {
    float4 v = *(const float4*)(src + i);
    bf16x4 o;
    o[0] = (bf16)v.x; o[1] = (bf16)v.y; o[2] = (bf16)v.z; o[3] = (bf16)v.w;
    *(bf16x4*)(dst + i) = o;
  }
}

// ---------------- RMSNorm * scale -> xn (bf16) ----------------
__global__ __launch_bounds__(256) void k_rmsnorm(const float* __restrict__ x,
                                                 const float* __restrict__ scl,
                                                 bf16* __restrict__ xn) {
  const int row = blockIdx.x, t = threadIdx.x;
  const int b = row / NL;
  const float* xr = x + (size_t)row * NDIM;
  float4 v = *(const float4*)(xr + t * 4);
  float ss = v.x*v.x + v.y*v.y + v.z*v.z + v.w*v.w;
#pragma unroll
  for (int o = 1; o < 64; o <<= 1) ss += __shfl_xor(ss, o);
  __shared__ float red[4];
  if ((t & 63) == 0) red[t >> 6] = ss;
  __syncthreads();
  const float tot = red[0] + red[1] + red[2] + red[3];
  const float rn = rsqrtf(tot * (1.0f / NDIM) + 1e-6f);
  const float4 sc = *(const float4*)(scl + b * NDIM + t * 4);
  bf16x4 o4;
  o4[0] = (bf16)(v.x * sc.x * rn);
  o4[1] = (bf16)(v.y * sc.y * rn);
  o4[2] = (bf16)(v.z * sc.z * rn);
  o4[3] = (bf16)(v.w * sc.w * rn);
  *(bf16x4*)(xn + (size_t)row * NDIM + t * 4) = o4;
}

// ---------------- GEMM: C[m,n] = sum_k A[m,k]*B[n,k]  (both row-major, B^T form) ----
// BK=64, proven XOR-granule swizzle (0 bank conflicts, R2-R8), 2-buffer
// counted-vmcnt pipeline: stage(t+1); vmcnt(8) [retires exactly stage(t)];
// barrier; ds_read+MFMA; barrier. stage(t+1)'s 8 loads stay in flight across
// compute. 1D grid with bijective XCD swizzle (nwg % 8 == 0 for our launches).
// EPI=0: store bf16; EPI=1: store f32 + skip add
template <int EPI>
__global__ __launch_bounds__(256) void k_gemm(const bf16* __restrict__ A,
                                              const bf16* __restrict__ Bm,
                                              int M, int N, int K,
                                              bf16* __restrict__ Cb,
                                              float* __restrict__ Cf,
                                              const float* __restrict__ skip) {
  __shared__ bf16 Als[2][128 * 64];
  __shared__ bf16 Bls[2][128 * 64];
  const int t = threadIdx.x;
  const int wave = t >> 6, lane = t & 63;
  const int g = lane >> 4, c = lane & 15;
  const int wm = wave >> 1, wn_ = wave & 1;

  const int nxb = N >> 7;
  const int nwg = gridDim.x;
  const int cpx = nwg >> 3;
  const int bid = blockIdx.x;
  const int swz = (nwg & 7) ? bid : (bid & 7) * cpx + (bid >> 3);  // XCD-grouped
  const int m0 = (swz / nxb) * 128, n0 = (swz % nxb) * 128;
  const int NT = K >> 6;

  const int srow = lane >> 3;                 // row within 8-row segment
  const int scol = ((lane & 7) ^ srow) * 8;   // pre-swizzled source granule

  f32x4 acc[4][4];
#pragma unroll
  for (int i = 0; i < 4; ++i)
#pragma unroll
    for (int j = 0; j < 4; ++j) acc[i][j] = f32x4{0.f, 0.f, 0.f, 0.f};

  auto stage = [&](int kt, int q) {
    const int k0 = kt << 6;
#pragma unroll
    for (int i = 0; i < 4; ++i) {
      const int seg = wave * 4 + i;
      int arow = m0 + seg * 8 + srow;
      if (arow >= M) arow = M - 1;
      gload16(A + (size_t)arow * K + k0 + scol, &Als[q][seg * 512]);
      const int brow = n0 + seg * 8 + srow;   // N % 128 == 0, no clamp
      gload16(Bm + (size_t)brow * K + k0 + scol, &Bls[q][seg * 512]);
    }
  };

  stage(0, 0);                                 // 8 loads in flight
  for (int kt = 0; kt < NT; ++kt) {
    const int cur = kt & 1;
    if (kt + 1 < NT) {
      stage(kt + 1, cur ^ 1);                  // 16 in flight
      asm volatile("s_waitcnt vmcnt(8)" ::: "memory");  // stage(kt) retired
    } else {
      asm volatile("s_waitcnt vmcnt(0)" ::: "memory");  // tail drain
    }
    __builtin_amdgcn_s_barrier();              // all waves' stage(kt) visible
    asm volatile("" ::: "memory");
#pragma unroll
    for (int kc = 0; kc < 2; ++kc) {
      bf16x8 af[4], bfr[4];
#pragma unroll
      for (int mi = 0; mi < 4; ++mi) {
        const int r = wm * 64 + mi * 16 + c;
        const int gg = ((kc * 4 + g) ^ (c & 7)) * 8;
        af[mi] = *(const bf16x8*)&Als[cur][r * 64 + gg];
      }
#pragma unroll
      for (int ni = 0; ni < 4; ++ni) {
        const int r = wn_ * 64 + ni * 16 + c;
        const int gg = ((kc * 4 + g) ^ (c & 7)) * 8;
        bfr[ni] = *(const bf16x8*)&Bls[cur][r * 64 + gg];
      }
      __builtin_amdgcn_s_setprio(1);
#pragma unroll
      for (int mi = 0; mi < 4; ++mi)
#pragma unroll
        for (int ni = 0; ni < 4; ++ni)
          acc[mi][ni] = __builtin_amdgcn_mfma_f32_16x16x32_bf16(af[mi], bfr[ni], acc[mi][ni], 0, 0, 0);
      __builtin_amdgcn_s_setprio(0);
    }
    asm volatile("" ::: "memory");
    __builtin_amdgcn_s_barrier();              // reads of buf done before overwrite
  }

#pragma unroll
  for (int mi = 0; mi < 4; ++mi) {
    const int rb = m0 + wm * 64 + mi * 16 + g * 4;
#pragma unroll
    for (int ni = 0; ni < 4; ++ni) {
      const int col = n0 + wn_ * 64 + ni * 16 + c;
#pragma unroll
      for (int j = 0; j < 4; ++j) {
        const int row = rb + j;
        if (row < M) {
          const size_t idx = (size_t)row * N + col;
          if (EPI == 0) Cb[idx] = (bf16)acc[mi][ni][j];
          else          Cf[idx] = acc[mi][ni][j] + skip[idx];
        }
      }
    }
  }
}

// ---------------- RoPE + layout reorg ----------------
__global__ __launch_bounds__(256) void k_rope(const bf16* __restrict__ qkv,
                                              const float* __restrict__ cosT,
                                              const float* __restrict__ sinT,
                                              bf16* __restrict__ qr,
                                              bf16* __restrict__ kr,
                                              bf16* __restrict__ vt) {
  __shared__ bf16 tq[64][64], tk[64][64], tv[64][64];
  const int blk = blockIdx.x;
  const int lt = blk % QTILES, bh = blk / QTILES;
  const int b = bh >> 4, h = bh & 15;
  const int l0 = lt * 64;
  const int t = threadIdx.x;
  const int row = t >> 2, ch = t & 3;
  const int c0 = ch * 16;
  const int l = l0 + row;
  const int lc = (l < NL) ? l : (NL - 1);
  const size_t base = ((size_t)(b * NL + lc)) * 3072 + h * 64 + c0;
  *(bf16x8*)&tq[row][c0]     = *(const bf16x8*)(qkv + base);
  *(bf16x8*)&tq[row][c0 + 8] = *(const bf16x8*)(qkv + base + 8);
  *(bf16x8*)&tk[row][c0]     = *(const bf16x8*)(qkv + base + 1024);
  *(bf16x8*)&tk[row][c0 + 8] = *(const bf16x8*)(qkv + base + 1032);
  *(bf16x8*)&tv[row][c0]     = *(const bf16x8*)(qkv + base + 2048);
  *(bf16x8*)&tv[row][c0 + 8] = *(const bf16x8*)(qkv + base + 2056);
  __syncthreads();

  if (l < NL) {
    bf16x8 vq0, vq1, vk0, vk1;
#pragma unroll
    for (int j = 0; j < 16; ++j) {
      const int d = c0 + j;
      float qv, kv;
      if (d < 16) {
        const float cf = cosT[l * 16 + d], sf = sinT[l * 16 + d];
        qv = (float)tq[row][d] * cf - (float)tq[row][d + 16] * sf;
        kv = (float)tk[row][d] * cf - (float)tk[row][d + 16] * sf;
      } else if (d < 32) {
        const float cf = cosT[l * 16 + d - 16], sf = sinT[l * 16 + d - 16];
        qv = (float)tq[row][d] * cf + (float)tq[row][d - 16] * sf;
        kv = (float)tk[row][d] * cf + (float)tk[row][d - 16] * sf;
      } else {
        qv = (float)tq[row][d];
        kv = (float)tk[row][d];
      }
      if (j < 8) { vq0[j] = (bf16)(qv * QSCALE); vk0[j] = (bf16)kv; }
      else       { vq1[j - 8] = (bf16)(qv * QSCALE); vk1[j - 8] = (bf16)kv; }
    }
    const size_t ob = ((size_t)bh * NL + l) * 64 + c0;
    *(bf16x8*)(qr + ob)     = vq0;
    *(bf16x8*)(qr + ob + 8) = vq1;
    *(bf16x8*)(kr + ob)     = vk0;
    *(bf16x8*)(kr + ob + 8) = vk1;
  }

  const int d = t >> 2, seg = t & 3;
  const int lb = l0 + seg * 16;
  if (lb + 15 < LP) {
    bf16x8 p0, p1;
#pragma unroll
    for (int i = 0; i < 8; ++i) p0[i] = tv[seg * 16 + i][d];
#pragma unroll
    for (int i = 0; i < 8; ++i) p1[i] = tv[seg * 16 + 8 + i][d];
    const size_t vb = ((size_t)bh * 64 + d) * LP + lb;
    *(bf16x8*)(vt + vb) = p0;
    *(bf16x8*)(vt + vb + 8) = p1;
  }
}

// ---------------- causal flash attention: 32x32 MFMA, swapped QK^T, no LDS ----
// One wave (64 threads) per 32-row q-tile slot. S^T = mfma32x32(A=K, B=Q):
// lane holds 16 scores for q-column (lane&31) -> mask/exp2/sum lane-local.
// P repacked in-register (cvt_pk_bf16 + lane-XOR-32). No-max softmax.
// Slot s<16 covers tiles {s, 31-s}; slot 16 covers {32} -> exactly 17
// kv-iterations per slot (perfect balance).
__global__ __launch_bounds__(64) void k_attn(const bf16* __restrict__ qr,
                                             const bf16* __restrict__ kr,
                                             const bf16* __restrict__ vt,
                                             bf16* __restrict__ oa) {
  const int bid = blockIdx.x;                    // grid = 4352 = 8 * 544
  const int lbid = (bid & 7) * (NBH * NSLOT / 8) + (bid >> 3);  // XCD-grouped
  const int slot = lbid % NSLOT, bh = lbid / NSLOT;
  const int b = bh >> 4, h = bh & 15;
  const int lane = threadIdx.x;
  const int ql = lane & 31;                      // q-col / kv-row / d-col index
  const int hh = lane >> 5;                      // half (k-chunk selector)
  const bf16* qb = qr + (size_t)bh * NL * 64;
  const bf16* kb = kr + (size_t)bh * NL * 64;
  const bf16* vb = vt + (size_t)bh * 64 * LP;

  auto run = [&](const int t) {
    const int q0 = t * 32;
    const int qabs = q0 + ql;
    const int qrow = (q0 + ql < NL) ? q0 + ql : NL - 1;
    bf16x8 bQ[4];
#pragma unroll
    for (int kc = 0; kc < 4; ++kc)
      bQ[kc] = *(const bf16x8*)(qb + (size_t)qrow * 64 + kc * 16 + hh * 8);

    f32x16 od0 = zero16(), od1 = zero16();
    float ls = 0.f;

    const int qmax = (q0 + 31 < NL - 1) ? q0 + 31 : NL - 1;
    const int nt = qmax / 64 + 1;

    bf16x8 aK[2][4];
    auto loadK = [&](int kv0) {
#pragma unroll
      for (int blk = 0; blk < 2; ++blk) {
        int r = kv0 + blk * 32 + ql; if (r >= NL) r = NL - 1;
        const bf16* kp = kb + (size_t)r * 64 + hh * 8;
#pragma unroll
        for (int kc = 0; kc < 4; ++kc)
          aK[blk][kc] = *(const bf16x8*)(kp + kc * 16);
      }
    };
    loadK(0);

    for (int tk = 0; tk < nt; ++tk) {
      const int kv0 = tk * 64;

      // V issued early; consumed after QK+softmax
      bf16x8 vf[2][4];
#pragma unroll
      for (int dblk = 0; dblk < 2; ++dblk) {
        const bf16* vp = vb + (size_t)(dblk * 32 + ql) * LP;
#pragma unroll
        for (int kc = 0; kc < 4; ++kc) {
          int col = kv0 + kc * 16 + hh * 8;
          if (col > LP - 8) col = LP - 8;     // final-tile clamp (P=0 there)
          vf[dblk][kc] = *(const bf16x8*)(vp + col);
        }
      }

      // QK^T (swapped): S^T[kv][q]
      f32x16 s0 = zero16(), s1 = zero16();
#pragma unroll
      for (int kc = 0; kc < 4; ++kc)
        s0 = __builtin_amdgcn_mfma_f32_32x32x16_bf16(aK[0][kc], bQ[kc], s0, 0, 0, 0);
#pragma unroll
      for (int kc = 0; kc < 4; ++kc)
        s1 = __builtin_amdgcn_mfma_f32_32x32x16_bf16(aK[1][kc], bQ[kc], s1, 0, 0, 0);

      // prefetch K(t+1) right after last use
      if (tk + 1 < nt) loadK(kv0 + 64);

      // softmax (no-max) + in-register repack to PV A-frags
      const bool needmask = (kv0 + 63 > q0);
      bf16x8 pa[4];
#pragma unroll
      for (int blk = 0; blk < 2; ++blk) {
        const f32x16& s = blk ? s1 : s0;
        float p[16];
#pragma unroll
        for (int r = 0; r < 16; ++r) {
          float v = s[r];
          if (needmask) {
            const int kvabs = kv0 + blk * 32 + (r & 3) + 8 * (r >> 2) + 4 * hh;
            if (kvabs > qabs) v = -1e30f;
          }
          p[r] = fexp2(v);
        }
        ls += (((p[0]+p[1])+(p[2]+p[3])) + ((p[4]+p[5])+(p[6]+p[7])))
            + (((p[8]+p[9])+(p[10]+p[11])) + ((p[12]+p[13])+(p[14]+p[15])));
        uint32_t w[8];
#pragma unroll
        for (int a = 0; a < 8; ++a) w[a] = cvtpk(p[2*a], p[2*a+1]);
        // exchange: send what the partner half needs
        const uint32_t sel0 = hh ? w[0] : w[2];
        const uint32_t sel1 = hh ? w[1] : w[3];
        const uint32_t sel2 = hh ? w[4] : w[6];
        const uint32_t sel3 = hh ? w[5] : w[7];
        const uint32_t ex0 = (uint32_t)__shfl_xor((int)sel0, 32);
        const uint32_t ex1 = (uint32_t)__shfl_xor((int)sel1, 32);
        const uint32_t ex2 = (uint32_t)__shfl_xor((int)sel2, 32);
        const uint32_t ex3 = (uint32_t)__shfl_xor((int)sel3, 32);
        u32x4 w0_, w1_;
        w0_[0] = hh ? ex0 : w[0];
        w0_[1] = hh ? ex1 : w[1];
        w0_[2] = hh ? w[2] : ex0;
        w0_[3] = hh ? w[3] : ex1;
        w1_[0] = hh ? ex2 : w[4];
        w1_[1] = hh ? ex3 : w[5];
        w1_[2] = hh ? w[6] : ex2;
        w1_[3] = hh ? w[7] : ex3;
        pa[2*blk]     = __builtin_bit_cast(bf16x8, w0_);
        pa[2*blk + 1] = __builtin_bit_cast(bf16x8, w1_);
      }

      // PV: O[q][d] += P[q][kv] * V[kv][d]
#pragma unroll
      for (int kc = 0; kc < 4; ++kc) {
        od0 = __builtin_amdgcn_mfma_f32_32x32x16_bf16(pa[kc], vf[0][kc], od0, 0, 0, 0);
        od1 = __builtin_amdgcn_mfma_f32_32x32x16_bf16(pa[kc], vf[1][kc], od1, 0, 0, 0);
      }
    }

    // finalize: total sum per q-column, redistribute inverse, store
    const float tot = ls + __shfl_xor(ls, 32);
    const float invOwn = 1.0f / tot;
#pragma unroll
    for (int r = 0; r < 16; ++r) {
      const int qrl = (r & 3) + 8 * (r >> 2) + 4 * hh;   // local q row of reg r
      const float inv = __shfl(invOwn, qrl);
      const int row = q0 + qrl;
      if (row < NL) {
        const size_t ob = (size_t)(b * NL + row) * NDIM + h * 64;
        oa[ob + ql]      = (bf16)(od0[r] * inv);
        oa[ob + 32 + ql] = (bf16)(od1[r] * inv);
      }
    }
  };

  if (slot < 16) { run(slot); run(31 - slot); }
  else           { run(32); }                     // slot 16: tile 32 only (17 iters)
}

extern "C" void kernel_launch(void* const* d_in, const int* in_sizes, int n_in,
                              void* d_out, int out_size, void* d_ws, size_t ws_size,
                              hipStream_t stream) {
  const float* x     = (const float*)d_in[0];
  const float* cond  = (const float*)d_in[1];
  const float* wnorm = (const float*)d_in[2];
  const float* wqkv  = (const float*)d_in[3];
  const float* wout  = (const float*)d_in[4];
  const float* cosT  = (const float*)d_in[5];
  const float* sinT  = (const float*)d_in[6];
  float* out = (float*)d_out;
  char* ws = (char*)d_ws;

  float* s_scl = (float*)(ws);                    //    65,536 B
  bf16*  s_wq  = (bf16*)(ws + 65536);             // 6,291,456 B
  bf16*  s_wo  = (bf16*)(ws + 6356992);           // 2,097,152 B
  bf16*  s_xn  = (bf16*)(ws + 8454144);           // 33,587,200 B (reused as attn out)
  bf16*  s_qkv = (bf16*)(ws + 42041344);          // 100,761,600 B
  bf16*  s_qr  = (bf16*)(ws + 142802944);         // 33,587,200 B
  bf16*  s_kr  = (bf16*)(ws + 176390144);         // 33,587,200 B
  bf16*  s_vt  = (bf16*)(ws + 209977344);         // 34,603,008 B -> end 244,580,352 B

  k_scale<<<NB, 256, 0, stream>>>(cond, wnorm, s_scl);
  k_cast<<<3072, 256, 0, stream>>>(wqkv, s_wq, 3 * NDIM * NDIM);
  k_cast<<<1024, 256, 0, stream>>>(wout, s_wo, NDIM * NDIM);
  k_rmsnorm<<<NML, 256, 0, stream>>>(x, s_scl, s_xn);
  k_gemm<0><<<3096, 256, 0, stream>>>(s_xn, s_wq, NML, 3 * NDIM, NDIM,
                                      s_qkv, nullptr, nullptr);
  k_rope<<<NBH * QTILES, 256, 0, stream>>>(s_qkv, cosT, sinT, s_qr, s_kr, s_vt);
  k_attn<<<NBH * NSLOT, 64, 0, stream>>>(s_qr, s_kr, s_vt, s_xn);
  k_gemm<1><<<1032, 256, 0, stream>>>(s_xn, s_wo, NML, NDIM, NDIM,
                                      nullptr, out, x);
}

// Round 12
// 433.954 us; speedup vs baseline: 1.2318x; 1.2318x over previous
//
#include <hip/hip_runtime.h>
#include <hip/hip_bf16.h>
#include <cstdint>

typedef __bf16 bf16;
typedef bf16 bf16x4 __attribute__((ext_vector_type(4)));
typedef bf16 bf16x8 __attribute__((ext_vector_type(8)));
typedef float f32x4 __attribute__((ext_vector_type(4)));
typedef float f32x16 __attribute__((ext_vector_type(16)));
typedef uint32_t u32x4 __attribute__((ext_vector_type(4)));

#define NB 16
#define NL 1025
#define NDIM 1024
#define NHEADS 16
#define NCOND 256
#define NBH (NB*NHEADS)       // 256
#define NML (NB*NL)           // 16400
#define LP 1056               // padded kv length for v^T rows
#define NSLOT 17              // attn: balanced 32-row q-tile slots per bh
#define QSCALE (0.125f * 1.44269504088896340736f)  // sm_scale * log2(e)

__device__ __forceinline__ void gload16(const void* g, void* l) {
  __builtin_amdgcn_global_load_lds(
      (const __attribute__((address_space(1))) void*)(uintptr_t)g,
      (__attribute__((address_space(3))) void*)(uintptr_t)l,
      16, 0, 0);
}

__device__ __forceinline__ float fexp2(float x) {
  return __builtin_amdgcn_exp2f(x);   // raw v_exp_f32; exp2(-1e30) -> 0
}

__device__ __forceinline__ uint32_t cvtpk(float lo, float hi) {
  uint32_t r;
  asm("v_cvt_pk_bf16_f32 %0, %1, %2" : "=v"(r) : "v"(lo), "v"(hi));
  return r;   // lo -> bits [15:0], hi -> bits [31:16]
}

__device__ __forceinline__ f32x16 zero16() {
  f32x16 z;
#pragma unroll
  for (int i = 0; i < 16; ++i) z[i] = 0.f;
  return z;
}

// ---------------- scale = cond @ w_norm^T + 1 ----------------
__global__ __launch_bounds__(256) void k_scale(const float* __restrict__ cond,
                                               const float* __restrict__ wn,
                                               float* __restrict__ scl) {
  __shared__ float cs[NCOND];
  const int b = blockIdx.x, t = threadIdx.x;
  cs[t] = cond[b * NCOND + t];
  __syncthreads();
#pragma unroll
  for (int dd = 0; dd < 4; ++dd) {
    const int d = t * 4 + dd;
    const float4* w = (const float4*)(wn + (size_t)d * NCOND);
    float acc = 1.0f;
    for (int c4 = 0; c4 < NCOND / 4; ++c4) {
      float4 wv = w[c4];
      acc += wv.x * cs[c4*4] + wv.y * cs[c4*4+1] + wv.z * cs[c4*4+2] + wv.w * cs[c4*4+3];
    }
    scl[b * NDIM + d] = acc;
  }
}

// ---------------- fp32 -> bf16 cast ----------------
__global__ __launch_bounds__(256) void k_cast(const float* __restrict__ src,
                                              bf16* __restrict__ dst, int n) {
  const int i = (blockIdx.x * 256 + threadIdx.x) * 4;
  if (i < n) {
    float4 v = *(const float4*)(src + i);
    bf16x4 o;
    o[0] = (bf16)v.x; o[1] = (bf16)v.y; o[2] = (bf16)v.z; o[3] = (bf16)v.w;
    *(bf16x4*)(dst + i) = o;
  }
}

// ---------------- RMSNorm * scale -> xn (bf16) ----------------
__global__ __launch_bounds__(256) void k_rmsnorm(const float* __restrict__ x,
                                                 const float* __restrict__ scl,
                                                 bf16* __restrict__ xn) {
  const int row = blockIdx.x, t = threadIdx.x;
  const int b = row / NL;
  const float* xr = x + (size_t)row * NDIM;
  float4 v = *(const float4*)(xr + t * 4);
  float ss = v.x*v.x + v.y*v.y + v.z*v.z + v.w*v.w;
#pragma unroll
  for (int o = 1; o < 64; o <<= 1) ss += __shfl_xor(ss, o);
  __shared__ float red[4];
  if ((t & 63) == 0) red[t >> 6] = ss;
  __syncthreads();
  const float tot = red[0] + red[1] + red[2] + red[3];
  const float rn = rsqrtf(tot * (1.0f / NDIM) + 1e-6f);
  const float4 sc = *(const float4*)(scl + b * NDIM + t * 4);
  bf16x4 o4;
  o4[0] = (bf16)(v.x * sc.x * rn);
  o4[1] = (bf16)(v.y * sc.y * rn);
  o4[2] = (bf16)(v.z * sc.z * rn);
  o4[3] = (bf16)(v.w * sc.w * rn);
  *(bf16x4*)(xn + (size_t)row * NDIM + t * 4) = o4;
}

// ---------------- GEMM: C[m,n] = sum_k A[m,k]*B[n,k]  (both row-major, B^T form) ----
// BK=64, XOR-granule swizzle (0 bank conflicts), 2-buffer counted-vmcnt pipeline:
// stage(t+1); vmcnt(8) [retires exactly stage(t)]; barrier; ds_read+MFMA; barrier.
// EPI=1: store f32 + skip add (out-proj).
// EPI=2: fused QKV epilogue — each wave's 64 cols = one (type, head); apply RoPE
//        in-register (pair d,d+16 = acc[mi][0]/acc[mi][1], cos/sin at [l*16+c]),
//        write qr/kr [bh][l][64] (q pre-scaled), V scatter-write to vt [bh][d][LP].
template <int EPI>
__global__ __launch_bounds__(256) void k_gemm(const bf16* __restrict__ A,
                                              const bf16* __restrict__ Bm,
                                              int M, int N, int K,
                                              float* __restrict__ Cf,
                                              const float* __restrict__ skip,
                                              bf16* __restrict__ qro,
                                              bf16* __restrict__ kro,
                                              bf16* __restrict__ vto,
                                              const float* __restrict__ cosT,
                                              const float* __restrict__ sinT) {
  __shared__ bf16 Als[2][128 * 64];
  __shared__ bf16 Bls[2][128 * 64];
  const int t = threadIdx.x;
  const int wave = t >> 6, lane = t & 63;
  const int g = lane >> 4, c = lane & 15;
  const int wm = wave >> 1, wn_ = wave & 1;

  const int nxb = N >> 7;
  const int nwg = gridDim.x;
  const int cpx = nwg >> 3;
  const int bid = blockIdx.x;
  const int swz = (nwg & 7) ? bid : (bid & 7) * cpx + (bid >> 3);  // XCD-grouped
  const int m0 = (swz / nxb) * 128, n0 = (swz % nxb) * 128;
  const int NT = K >> 6;

  const int srow = lane >> 3;                 // row within 8-row segment
  const int scol = ((lane & 7) ^ srow) * 8;   // pre-swizzled source granule

  f32x4 acc[4][4];
#pragma unroll
  for (int i = 0; i < 4; ++i)
#pragma unroll
    for (int j = 0; j < 4; ++j) acc[i][j] = f32x4{0.f, 0.f, 0.f, 0.f};

  auto stage = [&](int kt, int q) {
    const int k0 = kt << 6;
#pragma unroll
    for (int i = 0; i < 4; ++i) {
      const int seg = wave * 4 + i;
      int arow = m0 + seg * 8 + srow;
      if (arow >= M) arow = M - 1;
      gload16(A + (size_t)arow * K + k0 + scol, &Als[q][seg * 512]);
      const int brow = n0 + seg * 8 + srow;   // N % 128 == 0, no clamp
      gload16(Bm + (size_t)brow * K + k0 + scol, &Bls[q][seg * 512]);
    }
  };

  stage(0, 0);                                 // 8 loads in flight
  for (int kt = 0; kt < NT; ++kt) {
    const int cur = kt & 1;
    if (kt + 1 < NT) {
      stage(kt + 1, cur ^ 1);                  // 16 in flight
      asm volatile("s_waitcnt vmcnt(8)" ::: "memory");  // stage(kt) retired
    } else {
      asm volatile("s_waitcnt vmcnt(0)" ::: "memory");  // tail drain
    }
    __builtin_amdgcn_s_barrier();              // all waves' stage(kt) visible
    asm volatile("" ::: "memory");
#pragma unroll
    for (int kc = 0; kc < 2; ++kc) {
      bf16x8 af[4], bfr[4];
#pragma unroll
      for (int mi = 0; mi < 4; ++mi) {
        const int r = wm * 64 + mi * 16 + c;
        const int gg = ((kc * 4 + g) ^ (c & 7)) * 8;
        af[mi] = *(const bf16x8*)&Als[cur][r * 64 + gg];
      }
#pragma unroll
      for (int ni = 0; ni < 4; ++ni) {
        const int r = wn_ * 64 + ni * 16 + c;
        const int gg = ((kc * 4 + g) ^ (c & 7)) * 8;
        bfr[ni] = *(const bf16x8*)&Bls[cur][r * 64 + gg];
      }
      __builtin_amdgcn_s_setprio(1);
#pragma unroll
      for (int mi = 0; mi < 4; ++mi)
#pragma unroll
        for (int ni = 0; ni < 4; ++ni)
          acc[mi][ni] = __builtin_amdgcn_mfma_f32_16x16x32_bf16(af[mi], bfr[ni], acc[mi][ni], 0, 0, 0);
      __builtin_amdgcn_s_setprio(0);
    }
    asm volatile("" ::: "memory");
    __builtin_amdgcn_s_barrier();              // reads of buf done before overwrite
  }

  if (EPI == 1) {
#pragma unroll
    for (int mi = 0; mi < 4; ++mi) {
      const int rb = m0 + wm * 64 + mi * 16 + g * 4;
#pragma unroll
      for (int ni = 0; ni < 4; ++ni) {
        const int col = n0 + wn_ * 64 + ni * 16 + c;
#pragma unroll
        for (int j = 0; j < 4; ++j) {
          const int row = rb + j;
          if (row < M) {
            const size_t idx = (size_t)row * N + col;
            Cf[idx] = acc[mi][ni][j] + skip[idx];
          }
        }
      }
    }
  } else {
    // EPI==2: fused RoPE + layout epilogue
    const int ncol0 = n0 + wn_ * 64;
    const int type = ncol0 >> 10;              // 0=q, 1=k, 2=v
    const int hd = (ncol0 & 1023) >> 6;        // head
    if (type == 2) {
      // V: vt[bh][d][LP] with d = ni*16+c; 4 consecutive l per (mi) -> bf16x4
#pragma unroll
      for (int mi = 0; mi < 4; ++mi) {
        const int rb = m0 + wm * 64 + mi * 16 + g * 4;
        const int b0 = rb / NL, b3 = (rb + 3) / NL;
        if (rb + 3 < M && b0 == b3) {
          const int l0_ = rb - b0 * NL;
          const size_t bhb = (size_t)(b0 * NHEADS + hd) * 64;
#pragma unroll
          for (int ni = 0; ni < 4; ++ni) {
            const int d = ni * 16 + c;
            bf16x4 v4;
#pragma unroll
            for (int j = 0; j < 4; ++j) v4[j] = (bf16)acc[mi][ni][j];
            *(bf16x4*)(vto + (bhb + d) * LP + l0_) = v4;
          }
        } else {
#pragma unroll
          for (int j = 0; j < 4; ++j) {
            const int row = rb + j;
            if (row < M) {
              const int b_ = row / NL, l = row - b_ * NL;
              const size_t bhb = (size_t)(b_ * NHEADS + hd) * 64;
#pragma unroll
              for (int ni = 0; ni < 4; ++ni)
                vto[(bhb + ni * 16 + c) * LP + l] = (bf16)acc[mi][ni][j];
            }
          }
        }
      }
    } else {
      bf16* dst = (type == 0) ? qro : kro;
      const float qs = (type == 0) ? QSCALE : 1.0f;
#pragma unroll
      for (int mi = 0; mi < 4; ++mi) {
        const int rb = m0 + wm * 64 + mi * 16 + g * 4;
#pragma unroll
        for (int j = 0; j < 4; ++j) {
          const int row = rb + j;
          if (row < M) {
            const int b_ = row / NL, l = row - b_ * NL;
            const float cf = cosT[l * 16 + c], sf = sinT[l * 16 + c];
            const float a0 = acc[mi][0][j], a1 = acc[mi][1][j];
            const float r0 = (a0 * cf - a1 * sf) * qs;
            const float r1 = (a1 * cf + a0 * sf) * qs;
            const float r2 = acc[mi][2][j] * qs;
            const float r3 = acc[mi][3][j] * qs;
            const size_t bse = ((size_t)(b_ * NHEADS + hd) * NL + l) * 64;
            dst[bse + c]      = (bf16)r0;
            dst[bse + 16 + c] = (bf16)r1;
            dst[bse + 32 + c] = (bf16)r2;
            dst[bse + 48 + c] = (bf16)r3;
          }
        }
      }
    }
  }
}

// ---------------- causal flash attention: 32x32 MFMA, swapped QK^T, no LDS ----
// One wave (64 threads) per 32-row q-tile slot. S^T = mfma32x32(A=K, B=Q):
// lane holds 16 scores for q-column (lane&31) -> mask/exp2/sum lane-local.
// P repacked in-register (cvt_pk_bf16 + lane-XOR-32). No-max softmax.
// Slot s<16 covers tiles {s, 31-s}; slot 16 covers {32} -> exactly 17
// kv-iterations per slot (perfect balance).
__global__ __launch_bounds__(64) void k_attn(const bf16* __restrict__ qr,
                                             const bf16* __restrict__ kr,
                                             const bf16* __restrict__ vt,
                                             bf16* __restrict__ oa) {
  const int bid = blockIdx.x;                    // grid = 4352 = 8 * 544
  const int lbid = (bid & 7) * (NBH * NSLOT / 8) + (bid >> 3);  // XCD-grouped
  const int slot = lbid % NSLOT, bh = lbid / NSLOT;
  const int b = bh >> 4, h = bh & 15;
  const int lane = threadIdx.x;
  const int ql = lane & 31;                      // q-col / kv-row / d-col index
  const int hh = lane >> 5;                      // half (k-chunk selector)
  const bf16* qb = qr + (size_t)bh * NL * 64;
  const bf16* kb = kr + (size_t)bh * NL * 64;
  const bf16* vb = vt + (size_t)bh * 64 * LP;

  auto run = [&](const int t) {
    const int q0 = t * 32;
    const int qabs = q0 + ql;
    const int qrow = (q0 + ql < NL) ? q0 + ql : NL - 1;
    bf16x8 bQ[4];
#pragma unroll
    for (int kc = 0; kc < 4; ++kc)
      bQ[kc] = *(const bf16x8*)(qb + (size_t)qrow * 64 + kc * 16 + hh * 8);

    f32x16 od0 = zero16(), od1 = zero16();
    float ls = 0.f;

    const int qmax = (q0 + 31 < NL - 1) ? q0 + 31 : NL - 1;
    const int nt = qmax / 64 + 1;

    bf16x8 aK[2][4];
    auto loadK = [&](int kv0) {
#pragma unroll
      for (int blk = 0; blk < 2; ++blk) {
        int r = kv0 + blk * 32 + ql; if (r >= NL) r = NL - 1;
        const bf16* kp = kb + (size_t)r * 64 + hh * 8;
#pragma unroll
        for (int kc = 0; kc < 4; ++kc)
          aK[blk][kc] = *(const bf16x8*)(kp + kc * 16);
      }
    };
    loadK(0);

    for (int tk = 0; tk < nt; ++tk) {
      const int kv0 = tk * 64;

      // V issued early; consumed after QK+softmax
      bf16x8 vf[2][4];
#pragma unroll
      for (int dblk = 0; dblk < 2; ++dblk) {
        const bf16* vp = vb + (size_t)(dblk * 32 + ql) * LP;
#pragma unroll
        for (int kc = 0; kc < 4; ++kc) {
          int col = kv0 + kc * 16 + hh * 8;
          if (col > LP - 8) col = LP - 8;     // final-tile clamp (P=0 there)
          vf[dblk][kc] = *(const bf16x8*)(vp + col);
        }
      }

      // QK^T (swapped): S^T[kv][q]
      f32x16 s0 = zero16(), s1 = zero16();
#pragma unroll
      for (int kc = 0; kc < 4; ++kc)
        s0 = __builtin_amdgcn_mfma_f32_32x32x16_bf16(aK[0][kc], bQ[kc], s0, 0, 0, 0);
#pragma unroll
      for (int kc = 0; kc < 4; ++kc)
        s1 = __builtin_amdgcn_mfma_f32_32x32x16_bf16(aK[1][kc], bQ[kc], s1, 0, 0, 0);

      // prefetch K(t+1) right after last use
      if (tk + 1 < nt) loadK(kv0 + 64);

      // softmax (no-max) + in-register repack to PV A-frags
      const bool needmask = (kv0 + 63 > q0);
      bf16x8 pa[4];
#pragma unroll
      for (int blk = 0; blk < 2; ++blk) {
        const f32x16& s = blk ? s1 : s0;
        float p[16];
#pragma unroll
        for (int r = 0; r < 16; ++r) {
          float v = s[r];
          if (needmask) {
            const int kvabs = kv0 + blk * 32 + (r & 3) + 8 * (r >> 2) + 4 * hh;
            if (kvabs > qabs) v = -1e30f;
          }
          p[r] = fexp2(v);
        }
        ls += (((p[0]+p[1])+(p[2]+p[3])) + ((p[4]+p[5])+(p[6]+p[7])))
            + (((p[8]+p[9])+(p[10]+p[11])) + ((p[12]+p[13])+(p[14]+p[15])));
        uint32_t w[8];
#pragma unroll
        for (int a = 0; a < 8; ++a) w[a] = cvtpk(p[2*a], p[2*a+1]);
        // exchange: send what the partner half needs
        const uint32_t sel0 = hh ? w[0] : w[2];
        const uint32_t sel1 = hh ? w[1] : w[3];
        const uint32_t sel2 = hh ? w[4] : w[6];
        const uint32_t sel3 = hh ? w[5] : w[7];
        const uint32_t ex0 = (uint32_t)__shfl_xor((int)sel0, 32);
        const uint32_t ex1 = (uint32_t)__shfl_xor((int)sel1, 32);
        const uint32_t ex2 = (uint32_t)__shfl_xor((int)sel2, 32);
        const uint32_t ex3 = (uint32_t)__shfl_xor((int)sel3, 32);
        u32x4 w0_, w1_;
        w0_[0] = hh ? ex0 : w[0];
        w0_[1] = hh ? ex1 : w[1];
        w0_[2] = hh ? w[2] : ex0;
        w0_[3] = hh ? w[3] : ex1;
        w1_[0] = hh ? ex2 : w[4];
        w1_[1] = hh ? ex3 : w[5];
        w1_[2] = hh ? w[6] : ex2;
        w1_[3] = hh ? w[7] : ex3;
        pa[2*blk]     = __builtin_bit_cast(bf16x8, w0_);
        pa[2*blk + 1] = __builtin_bit_cast(bf16x8, w1_);
      }

      // PV: O[q][d] += P[q][kv] * V[kv][d]
#pragma unroll
      for (int kc = 0; kc < 4; ++kc) {
        od0 = __builtin_amdgcn_mfma_f32_32x32x16_bf16(pa[kc], vf[0][kc], od0, 0, 0, 0);
        od1 = __builtin_amdgcn_mfma_f32_32x32x16_bf16(pa[kc], vf[1][kc], od1, 0, 0, 0);
      }
    }

    // finalize: total sum per q-column, redistribute inverse, store
    const float tot = ls + __shfl_xor(ls, 32);
    const float invOwn = 1.0f / tot;
#pragma unroll
    for (int r = 0; r < 16; ++r) {
      const int qrl = (r & 3) + 8 * (r >> 2) + 4 * hh;   // local q row of reg r
      const float inv = __shfl(invOwn, qrl);
      const int row = q0 + qrl;
      if (row < NL) {
        const size_t ob = (size_t)(b * NL + row) * NDIM + h * 64;
        oa[ob + ql]      = (bf16)(od0[r] * inv);
        oa[ob + 32 + ql] = (bf16)(od1[r] * inv);
      }
    }
  };

  if (slot < 16) { run(slot); run(31 - slot); }
  else           { run(32); }                     // slot 16: tile 32 only (17 iters)
}

extern "C" void kernel_launch(void* const* d_in, const int* in_sizes, int n_in,
                              void* d_out, int out_size, void* d_ws, size_t ws_size,
                              hipStream_t stream) {
  const float* x     = (const float*)d_in[0];
  const float* cond  = (const float*)d_in[1];
  const float* wnorm = (const float*)d_in[2];
  const float* wqkv  = (const float*)d_in[3];
  const float* wout  = (const float*)d_in[4];
  const float* cosT  = (const float*)d_in[5];
  const float* sinT  = (const float*)d_in[6];
  float* out = (float*)d_out;
  char* ws = (char*)d_ws;

  float* s_scl = (float*)(ws);                    //    65,536 B
  bf16*  s_wq  = (bf16*)(ws + 65536);             // 6,291,456 B
  bf16*  s_wo  = (bf16*)(ws + 6356992);           // 2,097,152 B
  bf16*  s_xn  = (bf16*)(ws + 8454144);           // 33,587,200 B (reused as attn out)
  bf16*  s_qr  = (bf16*)(ws + 142802944);         // 33,587,200 B
  bf16*  s_kr  = (bf16*)(ws + 176390144);         // 33,587,200 B
  bf16*  s_vt  = (bf16*)(ws + 209977344);         // 34,603,008 B -> end 244,580,352 B

  k_scale<<<NB, 256, 0, stream>>>(cond, wnorm, s_scl);
  k_cast<<<3072, 256, 0, stream>>>(wqkv, s_wq, 3 * NDIM * NDIM);
  k_cast<<<1024, 256, 0, stream>>>(wout, s_wo, NDIM * NDIM);
  k_rmsnorm<<<NML, 256, 0, stream>>>(x, s_scl, s_xn);
  k_gemm<2><<<3096, 256, 0, stream>>>(s_xn, s_wq, NML, 3 * NDIM, NDIM,
                                      nullptr, nullptr, s_qr, s_kr, s_vt,
                                      cosT, sinT);
  k_attn<<<NBH * NSLOT, 64, 0, stream>>>(s_qr, s_kr, s_vt, s_xn);
  k_gemm<1><<<1032, 256, 0, stream>>>(s_xn, s_wo, NML, NDIM, NDIM,
                                      out, x, nullptr, nullptr, nullptr,
                                      nullptr, nullptr);
}

// Round 13
// 427.900 us; speedup vs baseline: 1.2492x; 1.0141x over previous
//
#include <hip/hip_runtime.h>
#include <hip/hip_bf16.h>
#include <cstdint>

typedef __bf16 bf16;
typedef bf16 bf16x4 __attribute__((ext_vector_type(4)));
typedef bf16 bf16x8 __attribute__((ext_vector_type(8)));
typedef float f32x4 __attribute__((ext_vector_type(4)));
typedef float f32x16 __attribute__((ext_vector_type(16)));
typedef uint32_t u32x4 __attribute__((ext_vector_type(4)));

#define NB 16
#define NL 1025
#define NDIM 1024
#define NHEADS 16
#define NCOND 256
#define NBH (NB*NHEADS)       // 256
#define NML (NB*NL)           // 16400
#define LP 1056               // padded kv length for v^T rows
#define NSLOT 17              // attn: balanced 32-row q-tile slots per bh
#define QSCALE (0.125f * 1.44269504088896340736f)  // sm_scale * log2(e)

__device__ __forceinline__ void gload16(const void* g, void* l) {
  __builtin_amdgcn_global_load_lds(
      (const __attribute__((address_space(1))) void*)(uintptr_t)g,
      (__attribute__((address_space(3))) void*)(uintptr_t)l,
      16, 0, 0);
}

__device__ __forceinline__ float fexp2(float x) {
  return __builtin_amdgcn_exp2f(x);   // raw v_exp_f32; exp2(-1e30) -> 0
}

__device__ __forceinline__ uint32_t cvtpk(float lo, float hi) {
  uint32_t r;
  asm("v_cvt_pk_bf16_f32 %0, %1, %2" : "=v"(r) : "v"(lo), "v"(hi));
  return r;   // lo -> bits [15:0], hi -> bits [31:16]
}

__device__ __forceinline__ f32x16 zero16() {
  f32x16 z;
#pragma unroll
  for (int i = 0; i < 16; ++i) z[i] = 0.f;
  return z;
}

// ---------------- scale = cond @ w_norm^T + 1 ----------------
__global__ __launch_bounds__(256) void k_scale(const float* __restrict__ cond,
                                               const float* __restrict__ wn,
                                               float* __restrict__ scl) {
  __shared__ float cs[NCOND];
  const int b = blockIdx.x, t = threadIdx.x;
  cs[t] = cond[b * NCOND + t];
  __syncthreads();
#pragma unroll
  for (int dd = 0; dd < 4; ++dd) {
    const int d = t * 4 + dd;
    const float4* w = (const float4*)(wn + (size_t)d * NCOND);
    float acc = 1.0f;
    for (int c4 = 0; c4 < NCOND / 4; ++c4) {
      float4 wv = w[c4];
      acc += wv.x * cs[c4*4] + wv.y * cs[c4*4+1] + wv.z * cs[c4*4+2] + wv.w * cs[c4*4+3];
    }
    scl[b * NDIM + d] = acc;
  }
}

// ---------------- fp32 -> bf16 cast ----------------
__global__ __launch_bounds__(256) void k_cast(const float* __restrict__ src,
                                              bf16* __restrict__ dst, int n) {
  const int i = (blockIdx.x * 256 + threadIdx.x) * 4;
  if (i < n) {
    float4 v = *(const float4*)(src + i);
    bf16x4 o;
    o[0] = (bf16)v.x; o[1] = (bf16)v.y; o[2] = (bf16)v.z; o[3] = (bf16)v.w;
    *(bf16x4*)(dst + i) = o;
  }
}

// ---------------- RMSNorm * scale -> xn (bf16) ----------------
__global__ __launch_bounds__(256) void k_rmsnorm(const float* __restrict__ x,
                                                 const float* __restrict__ scl,
                                                 bf16* __restrict__ xn) {
  const int row = blockIdx.x, t = threadIdx.x;
  const int b = row / NL;
  const float* xr = x + (size_t)row * NDIM;
  float4 v = *(const float4*)(xr + t * 4);
  float ss = v.x*v.x + v.y*v.y + v.z*v.z + v.w*v.w;
#pragma unroll
  for (int o = 1; o < 64; o <<= 1) ss += __shfl_xor(ss, o);
  __shared__ float red[4];
  if ((t & 63) == 0) red[t >> 6] = ss;
  __syncthreads();
  const float tot = red[0] + red[1] + red[2] + red[3];
  const float rn = rsqrtf(tot * (1.0f / NDIM) + 1e-6f);
  const float4 sc = *(const float4*)(scl + b * NDIM + t * 4);
  bf16x4 o4;
  o4[0] = (bf16)(v.x * sc.x * rn);
  o4[1] = (bf16)(v.y * sc.y * rn);
  o4[2] = (bf16)(v.z * sc.z * rn);
  o4[3] = (bf16)(v.w * sc.w * rn);
  *(bf16x4*)(xn + (size_t)row * NDIM + t * 4) = o4;
}

// ---------------- GEMM: C[m,n] = sum_k A[m,k]*B[n,k]  (both row-major, B^T form) ----
// BK=64, XOR-granule swizzle (0 bank conflicts), 2-buffer counted-vmcnt pipeline:
// stage(t+1); vmcnt(8) [retires exactly stage(t)]; barrier; ds_read+MFMA; barrier.
// EPI=1: store f32 + skip add (out-proj).
// EPI=2: fused QKV epilogue — each wave's 64 cols = one (type, head); apply RoPE
//        in-register (pair d,d+16 = acc[mi][0]/acc[mi][1], cos/sin at [l*16+c]),
//        write qr/kr [bh][l][64] (q pre-scaled), V scatter-write to vt [bh][d][LP].
template <int EPI>
__global__ __launch_bounds__(256) void k_gemm(const bf16* __restrict__ A,
                                              const bf16* __restrict__ Bm,
                                              int M, int N, int K,
                                              float* __restrict__ Cf,
                                              const float* __restrict__ skip,
                                              bf16* __restrict__ qro,
                                              bf16* __restrict__ kro,
                                              bf16* __restrict__ vto,
                                              const float* __restrict__ cosT,
                                              const float* __restrict__ sinT) {
  __shared__ bf16 Als[2][128 * 64];
  __shared__ bf16 Bls[2][128 * 64];
  const int t = threadIdx.x;
  const int wave = t >> 6, lane = t & 63;
  const int g = lane >> 4, c = lane & 15;
  const int wm = wave >> 1, wn_ = wave & 1;

  const int nxb = N >> 7;
  const int nwg = gridDim.x;
  const int cpx = nwg >> 3;
  const int bid = blockIdx.x;
  const int swz = (nwg & 7) ? bid : (bid & 7) * cpx + (bid >> 3);  // XCD-grouped
  const int m0 = (swz / nxb) * 128, n0 = (swz % nxb) * 128;
  const int NT = K >> 6;

  const int srow = lane >> 3;                 // row within 8-row segment
  const int scol = ((lane & 7) ^ srow) * 8;   // pre-swizzled source granule

  f32x4 acc[4][4];
#pragma unroll
  for (int i = 0; i < 4; ++i)
#pragma unroll
    for (int j = 0; j < 4; ++j) acc[i][j] = f32x4{0.f, 0.f, 0.f, 0.f};

  auto stage = [&](int kt, int q) {
    const int k0 = kt << 6;
#pragma unroll
    for (int i = 0; i < 4; ++i) {
      const int seg = wave * 4 + i;
      int arow = m0 + seg * 8 + srow;
      if (arow >= M) arow = M - 1;
      gload16(A + (size_t)arow * K + k0 + scol, &Als[q][seg * 512]);
      const int brow = n0 + seg * 8 + srow;   // N % 128 == 0, no clamp
      gload16(Bm + (size_t)brow * K + k0 + scol, &Bls[q][seg * 512]);
    }
  };

  stage(0, 0);                                 // 8 loads in flight
  for (int kt = 0; kt < NT; ++kt) {
    const int cur = kt & 1;
    if (kt + 1 < NT) {
      stage(kt + 1, cur ^ 1);                  // 16 in flight
      asm volatile("s_waitcnt vmcnt(8)" ::: "memory");  // stage(kt) retired
    } else {
      asm volatile("s_waitcnt vmcnt(0)" ::: "memory");  // tail drain
    }
    __builtin_amdgcn_s_barrier();              // all waves' stage(kt) visible
    asm volatile("" ::: "memory");
#pragma unroll
    for (int kc = 0; kc < 2; ++kc) {
      bf16x8 af[4], bfr[4];
#pragma unroll
      for (int mi = 0; mi < 4; ++mi) {
        const int r = wm * 64 + mi * 16 + c;
        const int gg = ((kc * 4 + g) ^ (c & 7)) * 8;
        af[mi] = *(const bf16x8*)&Als[cur][r * 64 + gg];
      }
#pragma unroll
      for (int ni = 0; ni < 4; ++ni) {
        const int r = wn_ * 64 + ni * 16 + c;
        const int gg = ((kc * 4 + g) ^ (c & 7)) * 8;
        bfr[ni] = *(const bf16x8*)&Bls[cur][r * 64 + gg];
      }
      __builtin_amdgcn_s_setprio(1);
#pragma unroll
      for (int mi = 0; mi < 4; ++mi)
#pragma unroll
        for (int ni = 0; ni < 4; ++ni)
          acc[mi][ni] = __builtin_amdgcn_mfma_f32_16x16x32_bf16(af[mi], bfr[ni], acc[mi][ni], 0, 0, 0);
      __builtin_amdgcn_s_setprio(0);
    }
    asm volatile("" ::: "memory");
    __builtin_amdgcn_s_barrier();              // reads of buf done before overwrite
  }

  if (EPI == 1) {
#pragma unroll
    for (int mi = 0; mi < 4; ++mi) {
      const int rb = m0 + wm * 64 + mi * 16 + g * 4;
#pragma unroll
      for (int ni = 0; ni < 4; ++ni) {
        const int col = n0 + wn_ * 64 + ni * 16 + c;
#pragma unroll
        for (int j = 0; j < 4; ++j) {
          const int row = rb + j;
          if (row < M) {
            const size_t idx = (size_t)row * N + col;
            Cf[idx] = acc[mi][ni][j] + skip[idx];
          }
        }
      }
    }
  } else {
    // EPI==2: fused RoPE + layout epilogue
    const int ncol0 = n0 + wn_ * 64;
    const int type = ncol0 >> 10;              // 0=q, 1=k, 2=v
    const int hd = (ncol0 & 1023) >> 6;        // head
    if (type == 2) {
      // V: vt[bh][d][LP] with d = ni*16+c; 4 consecutive l per (mi) -> bf16x4
#pragma unroll
      for (int mi = 0; mi < 4; ++mi) {
        const int rb = m0 + wm * 64 + mi * 16 + g * 4;
        const int b0 = rb / NL, b3 = (rb + 3) / NL;
        if (rb + 3 < M && b0 == b3) {
          const int l0_ = rb - b0 * NL;
          const size_t bhb = (size_t)(b0 * NHEADS + hd) * 64;
#pragma unroll
          for (int ni = 0; ni < 4; ++ni) {
            const int d = ni * 16 + c;
            bf16x4 v4;
#pragma unroll
            for (int j = 0; j < 4; ++j) v4[j] = (bf16)acc[mi][ni][j];
            *(bf16x4*)(vto + (bhb + d) * LP + l0_) = v4;
          }
        } else {
#pragma unroll
          for (int j = 0; j < 4; ++j) {
            const int row = rb + j;
            if (row < M) {
              const int b_ = row / NL, l = row - b_ * NL;
              const size_t bhb = (size_t)(b_ * NHEADS + hd) * 64;
#pragma unroll
              for (int ni = 0; ni < 4; ++ni)
                vto[(bhb + ni * 16 + c) * LP + l] = (bf16)acc[mi][ni][j];
            }
          }
        }
      }
    } else {
      bf16* dst = (type == 0) ? qro : kro;
      const float qs = (type == 0) ? QSCALE : 1.0f;
#pragma unroll
      for (int mi = 0; mi < 4; ++mi) {
        const int rb = m0 + wm * 64 + mi * 16 + g * 4;
#pragma unroll
        for (int j = 0; j < 4; ++j) {
          const int row = rb + j;
          if (row < M) {
            const int b_ = row / NL, l = row - b_ * NL;
            const float cf = cosT[l * 16 + c], sf = sinT[l * 16 + c];
            const float a0 = acc[mi][0][j], a1 = acc[mi][1][j];
            const float r0 = (a0 * cf - a1 * sf) * qs;
            const float r1 = (a1 * cf + a0 * sf) * qs;
            const float r2 = acc[mi][2][j] * qs;
            const float r3 = acc[mi][3][j] * qs;
            const size_t bse = ((size_t)(b_ * NHEADS + hd) * NL + l) * 64;
            dst[bse + c]      = (bf16)r0;
            dst[bse + 16 + c] = (bf16)r1;
            dst[bse + 32 + c] = (bf16)r2;
            dst[bse + 48 + c] = (bf16)r3;
          }
        }
      }
    }
  }
}

// ---------------- causal flash attention: dual-tile interleaved, no LDS ----
// One wave per slot; slot s<16 runs tiles {s, 31-s} INTERLEAVED in one kv loop
// (shared K/V loads; two independent MFMA/VALU chains per iteration for ILP);
// slot 16 runs tile 32 alone. S^T = mfma32x32(A=K, B=Q); lane holds 16 scores
// for q-col (lane&31); no-max softmax (exp2 via raw v_exp_f32); P repacked
// in-register via cvt_pk_bf16 + lane-XOR-32 exchange.
__global__ __launch_bounds__(64) void k_attn(const bf16* __restrict__ qr,
                                             const bf16* __restrict__ kr,
                                             const bf16* __restrict__ vt,
                                             bf16* __restrict__ oa) {
  const int bid = blockIdx.x;                    // grid = 4352 = 8 * 544
  const int lbid = (bid & 7) * (NBH * NSLOT / 8) + (bid >> 3);  // XCD-grouped
  const int slot = lbid % NSLOT, bh = lbid / NSLOT;
  const int b = bh >> 4, h = bh & 15;
  const int lane = threadIdx.x;
  const int ql = lane & 31;                      // q-col / kv-row / d-col index
  const int hh = lane >> 5;                      // half (k-chunk selector)
  const bf16* qb = qr + (size_t)bh * NL * 64;
  const bf16* kb = kr + (size_t)bh * NL * 64;
  const bf16* vb = vt + (size_t)bh * 64 * LP;

  const int tA = (slot < 16) ? slot : -1;
  const int tB = (slot < 16) ? 31 - slot : 32;
  const bool hasA = (tA >= 0);

  const int q0A = tA * 32, q0B = tB * 32;
  const int qabsA = q0A + ql, qabsB = q0B + ql;

  // Q fragments (B always; A when active)
  bf16x8 bQA[4], bQB[4];
  {
    const int qrB = (q0B + ql < NL) ? q0B + ql : NL - 1;
#pragma unroll
    for (int kc = 0; kc < 4; ++kc)
      bQB[kc] = *(const bf16x8*)(qb + (size_t)qrB * 64 + kc * 16 + hh * 8);
    const int qrA = hasA ? q0A + ql : 0;
#pragma unroll
    for (int kc = 0; kc < 4; ++kc)
      bQA[kc] = *(const bf16x8*)(qb + (size_t)qrA * 64 + kc * 16 + hh * 8);
  }

  f32x16 odA0 = zero16(), odA1 = zero16(), odB0 = zero16(), odB1 = zero16();
  float lsA = 0.f, lsB = 0.f;

  const int ntA = hasA ? ((q0A + 31) / 64 + 1) : 0;
  const int qmaxB = (q0B + 31 < NL - 1) ? q0B + 31 : NL - 1;
  const int ntB = qmaxB / 64 + 1;               // ntA <= ntB always

  bf16x8 aK[2][4];
  auto loadK = [&](int kv0) {
#pragma unroll
    for (int blk = 0; blk < 2; ++blk) {
      int r = kv0 + blk * 32 + ql; if (r >= NL) r = NL - 1;
      const bf16* kp = kb + (size_t)r * 64 + hh * 8;
#pragma unroll
      for (int kc = 0; kc < 4; ++kc)
        aK[blk][kc] = *(const bf16x8*)(kp + kc * 16);
    }
  };
  loadK(0);

  // softmax + in-register repack for one 64-kv tile of one q-tile
  auto smrepack = [&](const f32x16& s0, const f32x16& s1, int kv0, int q0,
                      int qabs, float& ls, bf16x8 (&pa)[4]) {
    const bool needmask = (kv0 + 63 > q0);
#pragma unroll
    for (int blk = 0; blk < 2; ++blk) {
      const f32x16& s = blk ? s1 : s0;
      float p[16];
#pragma unroll
      for (int r = 0; r < 16; ++r) {
        float v = s[r];
        if (needmask) {
          const int kvabs = kv0 + blk * 32 + (r & 3) + 8 * (r >> 2) + 4 * hh;
          if (kvabs > qabs) v = -1e30f;
        }
        p[r] = fexp2(v);
      }
      ls += (((p[0]+p[1])+(p[2]+p[3])) + ((p[4]+p[5])+(p[6]+p[7])))
          + (((p[8]+p[9])+(p[10]+p[11])) + ((p[12]+p[13])+(p[14]+p[15])));
      uint32_t w[8];
#pragma unroll
      for (int a = 0; a < 8; ++a) w[a] = cvtpk(p[2*a], p[2*a+1]);
      const uint32_t sel0 = hh ? w[0] : w[2];
      const uint32_t sel1 = hh ? w[1] : w[3];
      const uint32_t sel2 = hh ? w[4] : w[6];
      const uint32_t sel3 = hh ? w[5] : w[7];
      const uint32_t ex0 = (uint32_t)__shfl_xor((int)sel0, 32);
      const uint32_t ex1 = (uint32_t)__shfl_xor((int)sel1, 32);
      const uint32_t ex2 = (uint32_t)__shfl_xor((int)sel2, 32);
      const uint32_t ex3 = (uint32_t)__shfl_xor((int)sel3, 32);
      u32x4 w0_, w1_;
      w0_[0] = hh ? ex0 : w[0];
      w0_[1] = hh ? ex1 : w[1];
      w0_[2] = hh ? w[2] : ex0;
      w0_[3] = hh ? w[3] : ex1;
      w1_[0] = hh ? ex2 : w[4];
      w1_[1] = hh ? ex3 : w[5];
      w1_[2] = hh ? w[6] : ex2;
      w1_[3] = hh ? w[7] : ex3;
      pa[2*blk]     = __builtin_bit_cast(bf16x8, w0_);
      pa[2*blk + 1] = __builtin_bit_cast(bf16x8, w1_);
    }
  };

  for (int tk = 0; tk < ntB; ++tk) {
    const int kv0 = tk * 64;
    const bool actA = hasA && (tk < ntA);

    // shared V load (issued early; consumed after QK+softmax)
    bf16x8 vf[2][4];
#pragma unroll
    for (int dblk = 0; dblk < 2; ++dblk) {
      const bf16* vp = vb + (size_t)(dblk * 32 + ql) * LP;
#pragma unroll
      for (int kc = 0; kc < 4; ++kc) {
        int col = kv0 + kc * 16 + hh * 8;
        if (col > LP - 8) col = LP - 8;       // final-tile clamp (P=0 there)
        vf[dblk][kc] = *(const bf16x8*)(vp + col);
      }
    }

    // QK^T for A (if active), then softmax A -> paA
    bf16x8 paA[4];
    if (actA) {
      f32x16 s0 = zero16(), s1 = zero16();
#pragma unroll
      for (int kc = 0; kc < 4; ++kc)
        s0 = __builtin_amdgcn_mfma_f32_32x32x16_bf16(aK[0][kc], bQA[kc], s0, 0, 0, 0);
#pragma unroll
      for (int kc = 0; kc < 4; ++kc)
        s1 = __builtin_amdgcn_mfma_f32_32x32x16_bf16(aK[1][kc], bQA[kc], s1, 0, 0, 0);
      smrepack(s0, s1, kv0, q0A, qabsA, lsA, paA);
    }

    // QK^T for B + softmax B (A's PV below overlaps with this on the VALU side)
    f32x16 sB0 = zero16(), sB1 = zero16();
#pragma unroll
    for (int kc = 0; kc < 4; ++kc)
      sB0 = __builtin_amdgcn_mfma_f32_32x32x16_bf16(aK[0][kc], bQB[kc], sB0, 0, 0, 0);
#pragma unroll
    for (int kc = 0; kc < 4; ++kc)
      sB1 = __builtin_amdgcn_mfma_f32_32x32x16_bf16(aK[1][kc], bQB[kc], sB1, 0, 0, 0);

    // prefetch K(t+1) right after last QK use
    if (tk + 1 < ntB) loadK(kv0 + 64);

    // PV for A (independent of B's softmax -> overlaps)
    if (actA) {
#pragma unroll
      for (int kc = 0; kc < 4; ++kc) {
        odA0 = __builtin_amdgcn_mfma_f32_32x32x16_bf16(paA[kc], vf[0][kc], odA0, 0, 0, 0);
        odA1 = __builtin_amdgcn_mfma_f32_32x32x16_bf16(paA[kc], vf[1][kc], odA1, 0, 0, 0);
      }
    }

    bf16x8 paB[4];
    smrepack(sB0, sB1, kv0, q0B, qabsB, lsB, paB);

    // PV for B
#pragma unroll
    for (int kc = 0; kc < 4; ++kc) {
      odB0 = __builtin_amdgcn_mfma_f32_32x32x16_bf16(paB[kc], vf[0][kc], odB0, 0, 0, 0);
      odB1 = __builtin_amdgcn_mfma_f32_32x32x16_bf16(paB[kc], vf[1][kc], odB1, 0, 0, 0);
    }
  }

  // finalize + store (per tile)
  auto fin = [&](int q0, float ls, const f32x16& od0, const f32x16& od1) {
    const float tot = ls + __shfl_xor(ls, 32);
    const float invOwn = 1.0f / tot;
#pragma unroll
    for (int r = 0; r < 16; ++r) {
      const int qrl = (r & 3) + 8 * (r >> 2) + 4 * hh;   // local q row of reg r
      const float inv = __shfl(invOwn, qrl);
      const int row = q0 + qrl;
      if (row < NL) {
        const size_t ob = (size_t)(b * NL + row) * NDIM + h * 64;
        oa[ob + ql]      = (bf16)(od0[r] * inv);
        oa[ob + 32 + ql] = (bf16)(od1[r] * inv);
      }
    }
  };
  if (hasA) fin(q0A, lsA, odA0, odA1);
  fin(q0B, lsB, odB0, odB1);
}

extern "C" void kernel_launch(void* const* d_in, const int* in_sizes, int n_in,
                              void* d_out, int out_size, void* d_ws, size_t ws_size,
                              hipStream_t stream) {
  const float* x     = (const float*)d_in[0];
  const float* cond  = (const float*)d_in[1];
  const float* wnorm = (const float*)d_in[2];
  const float* wqkv  = (const float*)d_in[3];
  const float* wout  = (const float*)d_in[4];
  const float* cosT  = (const float*)d_in[5];
  const float* sinT  = (const float*)d_in[6];
  float* out = (float*)d_out;
  char* ws = (char*)d_ws;

  float* s_scl = (float*)(ws);                    //    65,536 B
  bf16*  s_wq  = (bf16*)(ws + 65536);             // 6,291,456 B
  bf16*  s_wo  = (bf16*)(ws + 6356992);           // 2,097,152 B
  bf16*  s_xn  = (bf16*)(ws + 8454144);           // 33,587,200 B (reused as attn out)
  bf16*  s_qr  = (bf16*)(ws + 142802944);         // 33,587,200 B
  bf16*  s_kr  = (bf16*)(ws + 176390144);         // 33,587,200 B
  bf16*  s_vt  = (bf16*)(ws + 209977344);         // 34,603,008 B -> end 244,580,352 B

  k_scale<<<NB, 256, 0, stream>>>(cond, wnorm, s_scl);
  k_cast<<<3072, 256, 0, stream>>>(wqkv, s_wq, 3 * NDIM * NDIM);
  k_cast<<<1024, 256, 0, stream>>>(wout, s_wo, NDIM * NDIM);
  k_rmsnorm<<<NML, 256, 0, stream>>>(x, s_scl, s_xn);
  k_gemm<2><<<3096, 256, 0, stream>>>(s_xn, s_wq, NML, 3 * NDIM, NDIM,
                                      nullptr, nullptr, s_qr, s_kr, s_vt,
                                      cosT, sinT);
  k_attn<<<NBH * NSLOT, 64, 0, stream>>>(s_qr, s_kr, s_vt, s_xn);
  k_gemm<1><<<1032, 256, 0, stream>>>(s_xn, s_wo, NML, NDIM, NDIM,
                                      out, x, nullptr, nullptr, nullptr,
                                      nullptr, nullptr);
}